// Round 1
// baseline (415.206 us; speedup 1.0000x reference)
//
#include <hip/hip_runtime.h>
#include <math.h>

typedef float f32x4 __attribute__((ext_vector_type(4)));
typedef short s16x8 __attribute__((ext_vector_type(8)));
typedef short s16x4 __attribute__((ext_vector_type(4)));

__device__ inline short f2bf(float f) {
    unsigned u = __float_as_uint(f);
    u = (u + 0x7fffu + ((u >> 16) & 1u)) >> 16;  // RNE
    return (short)(unsigned short)u;
}

// ---------------------------------------------------------------------------
// Kernel 1: pack weights -> WallT[n][k] bf16, n in [0,384) = f|g|h cols, k in [0,256)
// Transposed layout so MFMA A/B fragments read 16B contiguous along k.
// ---------------------------------------------------------------------------
__global__ __launch_bounds__(256) void wconv_kernel(
    const float* __restrict__ Wf, const float* __restrict__ Wg,
    const float* __restrict__ Wh, short* __restrict__ WallT)
{
    int t = blockIdx.x * 256 + threadIdx.x;   // 0..98303
    int n = t >> 8;
    int k = t & 255;
    float v;
    if (n < 64)       v = Wf[k * 64 + n];
    else if (n < 128) v = Wg[k * 64 + (n - 64)];
    else              v = Wh[k * 256 + (n - 128)];
    WallT[n * 256 + k] = f2bf(v);
}

// ---------------------------------------------------------------------------
// Kernel 2: projections. Per block: 64 pixels.
//   GEMM1: fg[p][0:128] = x @ [Wf|Wg] + [bf|bg]   (bf16 out, row-major, stride 128)
//   GEMM2: hT[b][c][n]  = (x @ Wh + bh)^T          (bf16 out, so attn reads V^T contiguously)
// ---------------------------------------------------------------------------
#define XQ_STRIDE 264   // 256 + 8 pad: 132 words, 4r%32 -> 2-way bank aliasing (free)

__global__ __launch_bounds__(256) void proj_kernel(
    const float* __restrict__ x, const short* __restrict__ WallT,
    const float* __restrict__ bfv, const float* __restrict__ bgv,
    const float* __restrict__ bhv,
    short* __restrict__ fg, short* __restrict__ hT)
{
    __shared__ short xq[64 * XQ_STRIDE];
    const int tid  = threadIdx.x;
    const int lane = tid & 63, w = tid >> 6;
    const int quad = lane >> 4, l15 = lane & 15;
    const int p0 = blockIdx.x * 64;

    // stage x (fp32) -> bf16 LDS tile [64][256]
    {
        int r = tid >> 2, q = tid & 3;
        const float* src = x + (size_t)(p0 + r) * 256 + q * 64;
        short* dst = xq + r * XQ_STRIDE + q * 64;
        for (int i = 0; i < 16; ++i) {
            f32x4 v = *(const f32x4*)(src + i * 4);
            s16x4 o;
            o[0] = f2bf(v[0]); o[1] = f2bf(v[1]); o[2] = f2bf(v[2]); o[3] = f2bf(v[3]);
            *(s16x4*)(dst + i * 4) = o;
        }
    }
    __syncthreads();

    // GEMM1: wave w owns pixel rows w*16..w*16+15, all 128 f|g cols
    {
        s16x8 af[8];
        const short* arow = xq + (w * 16 + l15) * XQ_STRIDE + quad * 8;
        for (int kk = 0; kk < 8; ++kk) af[kk] = *(const s16x8*)(arow + kk * 32);
        for (int nt = 0; nt < 8; ++nt) {
            f32x4 acc = {0.f, 0.f, 0.f, 0.f};
            const short* brow = WallT + (nt * 16 + l15) * 256 + quad * 8;
            for (int kk = 0; kk < 8; ++kk) {
                s16x8 bfr = *(const s16x8*)(brow + kk * 32);
                acc = __builtin_amdgcn_mfma_f32_16x16x32_bf16(af[kk], bfr, acc, 0, 0, 0);
            }
            int n = nt * 16 + l15;
            float bias = (n < 64) ? bfv[n] : bgv[n - 64];
            for (int r = 0; r < 4; ++r) {
                int p = p0 + w * 16 + quad * 4 + r;      // C/D: row=quad*4+r, col=l15
                fg[(size_t)p * 128 + n] = f2bf(acc[r] + bias);
            }
        }
    }

    // GEMM2: D[c][p] = sum_k Wh[k][c] * x[p][k]  (A = WallT rows 128+c, B = xq)
    // wave w owns c rows w*64..w*64+63; coalesced store of hT (col=pixel=l15)
    {
        for (int pt = 0; pt < 4; ++pt) {
            s16x8 bb[8];
            const short* brow = xq + (pt * 16 + l15) * XQ_STRIDE + quad * 8;
            for (int kk = 0; kk < 8; ++kk) bb[kk] = *(const s16x8*)(brow + kk * 32);
            for (int mt = 0; mt < 4; ++mt) {
                f32x4 acc = {0.f, 0.f, 0.f, 0.f};
                const short* arow = WallT + (size_t)(128 + w * 64 + mt * 16 + l15) * 256 + quad * 8;
                for (int kk = 0; kk < 8; ++kk) {
                    s16x8 aa = *(const s16x8*)(arow + kk * 32);
                    acc = __builtin_amdgcn_mfma_f32_16x16x32_bf16(aa, bb[kk], acc, 0, 0, 0);
                }
                int p  = p0 + pt * 16 + l15;
                int bt = p >> 12, npix = p & 4095;
                for (int r = 0; r < 4; ++r) {
                    int c = w * 64 + mt * 16 + quad * 4 + r;
                    hT[(size_t)(bt * 256 + c) * 4096 + npix] = f2bf(acc[r] + bhv[c]);
                }
            }
        }
    }
}

// ---------------------------------------------------------------------------
// Kernel 3: flash attention + fused residual epilogue.
// Grid: 4 batches * 64 q-tiles (64 queries each; 16 per wave). Loop 64-key tiles:
//   stage K[64][64] + V^T[256][64] in LDS; S via MFMA; online softmax
//   (16-lane shuffle reduce); P -> LDS (C-layout -> A-layout); O += P*V via MFMA.
// Epilogue: y = scale * (O / l) + x   (fp32)
// ---------------------------------------------------------------------------
#define KV_STRIDE 72    // 64 + 8 pad: 36 words, 4r%32 -> 2-way aliasing (free)

__global__ __launch_bounds__(256) void attn_kernel(
    const short* __restrict__ fg, const short* __restrict__ hT,
    const float* __restrict__ xin, const float* __restrict__ scale_p,
    float* __restrict__ out)
{
    __shared__ short Klds[64 * KV_STRIDE];        //  9.2 KB
    __shared__ short Vlds[256 * KV_STRIDE];       // 36.9 KB
    __shared__ short Plds[4 * 16 * KV_STRIDE];    //  9.2 KB (per-wave slices)

    const int tid  = threadIdx.x;
    const int lane = tid & 63, w = tid >> 6;
    const int quad = lane >> 4, l15 = lane & 15;
    const int b  = blockIdx.x >> 6;
    const int q0 = (blockIdx.x & 63) * 64;

    // persistent Q A-fragments (g = cols 64..127 of fg); A[m=l15][k=quad*8+j]
    const short* qptr = fg + (size_t)(b * 4096 + q0 + w * 16 + l15) * 128 + 64 + quad * 8;
    s16x8 qf0 = *(const s16x8*)(qptr);
    s16x8 qf1 = *(const s16x8*)(qptr + 32);

    float m_r[4], l_r[4];
    f32x4 oacc[16];
    const f32x4 zac = {0.f, 0.f, 0.f, 0.f};
    for (int r = 0; r < 4; ++r) { m_r[r] = -INFINITY; l_r[r] = 0.f; }
    for (int ct = 0; ct < 16; ++ct) oacc[ct] = zac;

    for (int m0 = 0; m0 < 4096; m0 += 64) {
        // stage K tile (f = cols 0..63 of fg) and V^T tile (hT rows, contiguous in m)
        for (int i = 0; i < 2; ++i) {
            int cid = tid + i * 256;
            int row = cid >> 3, seg = cid & 7;
            *(s16x8*)(Klds + row * KV_STRIDE + seg * 8) =
                *(const s16x8*)(fg + (size_t)(b * 4096 + m0 + row) * 128 + seg * 8);
        }
        for (int i = 0; i < 8; ++i) {
            int cid = tid + i * 256;
            int row = cid >> 3, seg = cid & 7;
            *(s16x8*)(Vlds + row * KV_STRIDE + seg * 8) =
                *(const s16x8*)(hT + (size_t)(b * 256 + row) * 4096 + m0 + seg * 8);
        }
        __syncthreads();

        // S[q][key]: 16 q-rows x 64 keys per wave; B-frag = K rows (B[k=d][n=key])
        f32x4 s[4];
        for (int nt = 0; nt < 4; ++nt) {
            const short* kp = Klds + (nt * 16 + l15) * KV_STRIDE + quad * 8;
            s16x8 kb0 = *(const s16x8*)(kp);
            s16x8 kb1 = *(const s16x8*)(kp + 32);
            f32x4 z = zac;
            z     = __builtin_amdgcn_mfma_f32_16x16x32_bf16(qf0, kb0, z, 0, 0, 0);
            s[nt] = __builtin_amdgcn_mfma_f32_16x16x32_bf16(qf1, kb1, z, 0, 0, 0);
        }

        // online softmax; C/D layout: col=l15 (key), row=quad*4+r (query)
        for (int r = 0; r < 4; ++r) {
            float mx = fmaxf(fmaxf(s[0][r], s[1][r]), fmaxf(s[2][r], s[3][r]));
            mx = fmaxf(mx, __shfl_xor(mx, 1, 64));
            mx = fmaxf(mx, __shfl_xor(mx, 2, 64));
            mx = fmaxf(mx, __shfl_xor(mx, 4, 64));
            mx = fmaxf(mx, __shfl_xor(mx, 8, 64));
            float mn = fmaxf(m_r[r], mx);
            float alpha = __expf(m_r[r] - mn);
            m_r[r] = mn;
            float sum = 0.f;
            float p0v = __expf(s[0][r] - mn); s[0][r] = p0v; sum += p0v;
            float p1v = __expf(s[1][r] - mn); s[1][r] = p1v; sum += p1v;
            float p2v = __expf(s[2][r] - mn); s[2][r] = p2v; sum += p2v;
            float p3v = __expf(s[3][r] - mn); s[3][r] = p3v; sum += p3v;
            sum += __shfl_xor(sum, 1, 64);
            sum += __shfl_xor(sum, 2, 64);
            sum += __shfl_xor(sum, 4, 64);
            sum += __shfl_xor(sum, 8, 64);
            l_r[r] = l_r[r] * alpha + sum;
            for (int ct = 0; ct < 16; ++ct) oacc[ct][r] *= alpha;
            short* prow = Plds + (w * 16 + quad * 4 + r) * KV_STRIDE + l15;
            prow[0]  = f2bf(s[0][r]);
            prow[16] = f2bf(s[1][r]);
            prow[32] = f2bf(s[2][r]);
            prow[48] = f2bf(s[3][r]);
        }

        // O += P V: P A-frag from LDS (A[m=l15][k=quad*8+j]); B-frag = V^T rows
        const short* pp = Plds + (w * 16 + l15) * KV_STRIDE + quad * 8;
        s16x8 pa0 = *(const s16x8*)(pp);
        s16x8 pa1 = *(const s16x8*)(pp + 32);
        for (int ct = 0; ct < 16; ++ct) {
            const short* vp = Vlds + (ct * 16 + l15) * KV_STRIDE + quad * 8;
            s16x8 vb0 = *(const s16x8*)(vp);
            s16x8 vb1 = *(const s16x8*)(vp + 32);
            oacc[ct] = __builtin_amdgcn_mfma_f32_16x16x32_bf16(pa0, vb0, oacc[ct], 0, 0, 0);
            oacc[ct] = __builtin_amdgcn_mfma_f32_16x16x32_bf16(pa1, vb1, oacc[ct], 0, 0, 0);
        }
        __syncthreads();
    }

    // epilogue: y = scale * (O / l) + x
    const float scale = *scale_p;
    float linv[4];
    for (int r = 0; r < 4; ++r) linv[r] = 1.f / l_r[r];
    for (int ct = 0; ct < 16; ++ct) {
        for (int r = 0; r < 4; ++r) {
            int p = b * 4096 + q0 + w * 16 + quad * 4 + r;
            size_t idx = (size_t)p * 256 + ct * 16 + l15;
            out[idx] = scale * (oacc[ct][r] * linv[r]) + xin[idx];
        }
    }
}

// ---------------------------------------------------------------------------
extern "C" void kernel_launch(void* const* d_in, const int* in_sizes, int n_in,
                              void* d_out, int out_size, void* d_ws, size_t ws_size,
                              hipStream_t stream) {
    (void)in_sizes; (void)n_in; (void)out_size; (void)ws_size;
    const float* x     = (const float*)d_in[0];
    const float* Wf    = (const float*)d_in[1];
    const float* bfv   = (const float*)d_in[2];
    const float* Wg    = (const float*)d_in[3];
    const float* bgv   = (const float*)d_in[4];
    const float* Wh    = (const float*)d_in[5];
    const float* bhv   = (const float*)d_in[6];
    const float* scale = (const float*)d_in[7];
    float* out = (float*)d_out;

    // workspace layout (bf16 as short)
    short* WallT = (short*)d_ws;            // 384*256
    short* fg    = WallT + 384 * 256;       // 16384*128
    short* hT    = fg + 16384 * 128;        // 4*256*4096

    wconv_kernel<<<384, 256, 0, stream>>>(Wf, Wg, Wh, WallT);
    proj_kernel<<<256, 256, 0, stream>>>(x, WallT, bfv, bgv, bhv, fg, hT);
    attn_kernel<<<256, 256, 0, stream>>>(fg, hT, x, scale, out);
}

// Round 2
// 262.076 us; speedup vs baseline: 1.5843x; 1.5843x over previous
//
#include <hip/hip_runtime.h>
#include <math.h>

typedef float f32x4 __attribute__((ext_vector_type(4)));
typedef short s16x8 __attribute__((ext_vector_type(8)));
typedef short s16x4 __attribute__((ext_vector_type(4)));

__device__ inline short f2bf(float f) {
    unsigned u = __float_as_uint(f);
    u = (u + 0x7fffu + ((u >> 16) & 1u)) >> 16;  // RNE
    return (short)(unsigned short)u;
}

// ---------------------------------------------------------------------------
// Kernel 1: pack weights -> WallT[n][k] bf16, n in [0,384) = f|g|h cols, k in [0,256)
// ---------------------------------------------------------------------------
__global__ __launch_bounds__(256) void wconv_kernel(
    const float* __restrict__ Wf, const float* __restrict__ Wg,
    const float* __restrict__ Wh, short* __restrict__ WallT)
{
    int t = blockIdx.x * 256 + threadIdx.x;   // 0..98303
    int n = t >> 8;
    int k = t & 255;
    float v;
    if (n < 64)       v = Wf[k * 64 + n];
    else if (n < 128) v = Wg[k * 64 + (n - 64)];
    else              v = Wh[k * 256 + (n - 128)];
    WallT[n * 256 + k] = f2bf(v);
}

// ---------------------------------------------------------------------------
// Kernel 2: projections. 512 blocks x 128 threads (2 waves), 32 pixels/block.
//   GEMM1: fg[p][0:128] = x @ [Wf|Wg] + [bf|bg]   (bf16, row-major, stride 128)
//   GEMM2: hT[b][c][n]  = (x @ Wh + bh)^T          (bf16, V^T layout for attn)
// ---------------------------------------------------------------------------
#define XQ_STRIDE 264   // 256 + 8 pad

__global__ __launch_bounds__(128) void proj_kernel(
    const float* __restrict__ x, const short* __restrict__ WallT,
    const float* __restrict__ bfv, const float* __restrict__ bgv,
    const float* __restrict__ bhv,
    short* __restrict__ fg, short* __restrict__ hT)
{
    __shared__ short xq[32 * XQ_STRIDE];   // ~16.9 KB
    const int tid  = threadIdx.x;
    const int lane = tid & 63, w = tid >> 6;        // w in {0,1}
    const int quad = lane >> 4, l15 = lane & 15;
    const int p0 = blockIdx.x * 32;

    // stage x (fp32) -> bf16 LDS tile [32][256]
    {
        int r = tid >> 2, q = tid & 3;              // r 0..31
        const float* src = x + (size_t)(p0 + r) * 256 + q * 64;
        short* dst = xq + r * XQ_STRIDE + q * 64;
        for (int i = 0; i < 16; ++i) {
            f32x4 v = *(const f32x4*)(src + i * 4);
            s16x4 o;
            o[0] = f2bf(v[0]); o[1] = f2bf(v[1]); o[2] = f2bf(v[2]); o[3] = f2bf(v[3]);
            *(s16x4*)(dst + i * 4) = o;
        }
    }
    __syncthreads();

    // GEMM1: wave w owns pixel rows w*16..w*16+15, all 128 f|g cols
    {
        s16x8 af[8];
        const short* arow = xq + (w * 16 + l15) * XQ_STRIDE + quad * 8;
        for (int kk = 0; kk < 8; ++kk) af[kk] = *(const s16x8*)(arow + kk * 32);
        for (int nt = 0; nt < 8; ++nt) {
            f32x4 acc = {0.f, 0.f, 0.f, 0.f};
            const short* brow = WallT + (nt * 16 + l15) * 256 + quad * 8;
            for (int kk = 0; kk < 8; ++kk) {
                s16x8 bfr = *(const s16x8*)(brow + kk * 32);
                acc = __builtin_amdgcn_mfma_f32_16x16x32_bf16(af[kk], bfr, acc, 0, 0, 0);
            }
            int n = nt * 16 + l15;
            float bias = (n < 64) ? bfv[n] : bgv[n - 64];
            for (int r = 0; r < 4; ++r) {
                int p = p0 + w * 16 + quad * 4 + r;      // C/D: row=quad*4+r, col=l15
                fg[(size_t)p * 128 + n] = f2bf(acc[r] + bias);
            }
        }
    }

    // GEMM2: D[c][p] = sum_k Wh[k][c] * x[p][k]; wave w owns c in [w*128, w*128+128)
    {
        for (int pt = 0; pt < 2; ++pt) {
            s16x8 bb[8];
            const short* brow = xq + (pt * 16 + l15) * XQ_STRIDE + quad * 8;
            for (int kk = 0; kk < 8; ++kk) bb[kk] = *(const s16x8*)(brow + kk * 32);
            for (int mt = 0; mt < 8; ++mt) {
                f32x4 acc = {0.f, 0.f, 0.f, 0.f};
                const short* arow = WallT + (size_t)(128 + w * 128 + mt * 16 + l15) * 256 + quad * 8;
                for (int kk = 0; kk < 8; ++kk) {
                    s16x8 aa = *(const s16x8*)(arow + kk * 32);
                    acc = __builtin_amdgcn_mfma_f32_16x16x32_bf16(aa, bb[kk], acc, 0, 0, 0);
                }
                int p  = p0 + pt * 16 + l15;
                int bt = p >> 12, npix = p & 4095;
                for (int r = 0; r < 4; ++r) {
                    int c = w * 128 + mt * 16 + quad * 4 + r;
                    hT[(size_t)(bt * 256 + c) * 4096 + npix] = f2bf(acc[r] + bhv[c]);
                }
            }
        }
    }
}

// ---------------------------------------------------------------------------
// Kernel 3: flash attention + fused residual epilogue, channel-split x2.
// Grid: 4 batches * 64 q-tiles * 2 channel-halves = 512 blocks (256 thr).
// Each block: 64 queries (16/wave), O over 128 of 256 channels. QK + softmax
// recomputed by both halves (cheap); V-LDS halves -> 36.9 KB/block
// -> 4 blocks/CU capacity, >=2 resident (vs 1 before).
// ---------------------------------------------------------------------------
#define KV_STRIDE 72    // 64 + 8 pad

__global__ __launch_bounds__(256) void attn_kernel(
    const short* __restrict__ fg, const short* __restrict__ hT,
    const float* __restrict__ xin, const float* __restrict__ scale_p,
    float* __restrict__ out)
{
    __shared__ short Klds[64 * KV_STRIDE];        //  9.2 KB
    __shared__ short Vlds[128 * KV_STRIDE];       // 18.4 KB (channel half)
    __shared__ short Plds[4 * 16 * KV_STRIDE];    //  9.2 KB (per-wave slices)

    const int tid  = threadIdx.x;
    const int lane = tid & 63, w = tid >> 6;
    const int quad = lane >> 4, l15 = lane & 15;
    const int b   = blockIdx.x >> 7;              // batch
    const int rem = blockIdx.x & 127;
    const int q0  = (rem >> 1) * 64;              // query tile base
    const int ch0 = (rem & 1) * 128;              // channel half base

    // persistent Q A-fragments (g = cols 64..127 of fg); A[m=l15][k=quad*8+j]
    const short* qptr = fg + (size_t)(b * 4096 + q0 + w * 16 + l15) * 128 + 64 + quad * 8;
    s16x8 qf0 = *(const s16x8*)(qptr);
    s16x8 qf1 = *(const s16x8*)(qptr + 32);

    float m_r[4], l_r[4];
    f32x4 oacc[8];
    const f32x4 zac = {0.f, 0.f, 0.f, 0.f};
    for (int r = 0; r < 4; ++r) { m_r[r] = -INFINITY; l_r[r] = 0.f; }
    for (int ct = 0; ct < 8; ++ct) oacc[ct] = zac;

    for (int m0 = 0; m0 < 4096; m0 += 64) {
        // stage K tile (f = cols 0..63 of fg)
        for (int i = 0; i < 2; ++i) {
            int cid = tid + i * 256;
            int row = cid >> 3, seg = cid & 7;
            *(s16x8*)(Klds + row * KV_STRIDE + seg * 8) =
                *(const s16x8*)(fg + (size_t)(b * 4096 + m0 + row) * 128 + seg * 8);
        }
        // stage V^T tile: rows = channels ch0..ch0+127, cols = keys m0..m0+63
        for (int i = 0; i < 4; ++i) {
            int cid = tid + i * 256;
            int row = cid >> 3, seg = cid & 7;
            *(s16x8*)(Vlds + row * KV_STRIDE + seg * 8) =
                *(const s16x8*)(hT + (size_t)(b * 256 + ch0 + row) * 4096 + m0 + seg * 8);
        }
        __syncthreads();

        // S[q][key]: 16 q-rows x 64 keys per wave
        f32x4 s[4];
        for (int nt = 0; nt < 4; ++nt) {
            const short* kp = Klds + (nt * 16 + l15) * KV_STRIDE + quad * 8;
            s16x8 kb0 = *(const s16x8*)(kp);
            s16x8 kb1 = *(const s16x8*)(kp + 32);
            f32x4 z = zac;
            z     = __builtin_amdgcn_mfma_f32_16x16x32_bf16(qf0, kb0, z, 0, 0, 0);
            s[nt] = __builtin_amdgcn_mfma_f32_16x16x32_bf16(qf1, kb1, z, 0, 0, 0);
        }

        // online softmax; C/D layout: col=l15 (key), row=quad*4+r (query)
        for (int r = 0; r < 4; ++r) {
            float mx = fmaxf(fmaxf(s[0][r], s[1][r]), fmaxf(s[2][r], s[3][r]));
            mx = fmaxf(mx, __shfl_xor(mx, 1, 64));
            mx = fmaxf(mx, __shfl_xor(mx, 2, 64));
            mx = fmaxf(mx, __shfl_xor(mx, 4, 64));
            mx = fmaxf(mx, __shfl_xor(mx, 8, 64));
            float mn = fmaxf(m_r[r], mx);
            float alpha = __expf(m_r[r] - mn);
            m_r[r] = mn;
            float sum = 0.f;
            float p0v = __expf(s[0][r] - mn); s[0][r] = p0v; sum += p0v;
            float p1v = __expf(s[1][r] - mn); s[1][r] = p1v; sum += p1v;
            float p2v = __expf(s[2][r] - mn); s[2][r] = p2v; sum += p2v;
            float p3v = __expf(s[3][r] - mn); s[3][r] = p3v; sum += p3v;
            sum += __shfl_xor(sum, 1, 64);
            sum += __shfl_xor(sum, 2, 64);
            sum += __shfl_xor(sum, 4, 64);
            sum += __shfl_xor(sum, 8, 64);
            l_r[r] = l_r[r] * alpha + sum;
            for (int ct = 0; ct < 8; ++ct) oacc[ct][r] *= alpha;
            short* prow = Plds + (w * 16 + quad * 4 + r) * KV_STRIDE + l15;
            prow[0]  = f2bf(s[0][r]);
            prow[16] = f2bf(s[1][r]);
            prow[32] = f2bf(s[2][r]);
            prow[48] = f2bf(s[3][r]);
        }

        // O += P V over 128 channels: P A-frag from LDS; B-frag = V^T rows
        const short* pp = Plds + (w * 16 + l15) * KV_STRIDE + quad * 8;
        s16x8 pa0 = *(const s16x8*)(pp);
        s16x8 pa1 = *(const s16x8*)(pp + 32);
        for (int ct = 0; ct < 8; ++ct) {
            const short* vp = Vlds + (ct * 16 + l15) * KV_STRIDE + quad * 8;
            s16x8 vb0 = *(const s16x8*)(vp);
            s16x8 vb1 = *(const s16x8*)(vp + 32);
            oacc[ct] = __builtin_amdgcn_mfma_f32_16x16x32_bf16(pa0, vb0, oacc[ct], 0, 0, 0);
            oacc[ct] = __builtin_amdgcn_mfma_f32_16x16x32_bf16(pa1, vb1, oacc[ct], 0, 0, 0);
        }
        __syncthreads();
    }

    // epilogue: y = scale * (O / l) + x   (channels ch0..ch0+127 only)
    const float scale = *scale_p;
    float linv[4];
    for (int r = 0; r < 4; ++r) linv[r] = 1.f / l_r[r];
    for (int ct = 0; ct < 8; ++ct) {
        for (int r = 0; r < 4; ++r) {
            int p = b * 4096 + q0 + w * 16 + quad * 4 + r;
            size_t idx = (size_t)p * 256 + ch0 + ct * 16 + l15;
            out[idx] = scale * (oacc[ct][r] * linv[r]) + xin[idx];
        }
    }
}

// ---------------------------------------------------------------------------
extern "C" void kernel_launch(void* const* d_in, const int* in_sizes, int n_in,
                              void* d_out, int out_size, void* d_ws, size_t ws_size,
                              hipStream_t stream) {
    (void)in_sizes; (void)n_in; (void)out_size; (void)ws_size;
    const float* x     = (const float*)d_in[0];
    const float* Wf    = (const float*)d_in[1];
    const float* bfv   = (const float*)d_in[2];
    const float* Wg    = (const float*)d_in[3];
    const float* bgv   = (const float*)d_in[4];
    const float* Wh    = (const float*)d_in[5];
    const float* bhv   = (const float*)d_in[6];
    const float* scale = (const float*)d_in[7];
    float* out = (float*)d_out;

    // workspace layout (bf16 as short)
    short* WallT = (short*)d_ws;            // 384*256
    short* fg    = WallT + 384 * 256;       // 16384*128
    short* hT    = fg + 16384 * 128;        // 4*256*4096

    wconv_kernel<<<384, 256, 0, stream>>>(Wf, Wg, Wh, WallT);
    proj_kernel<<<512, 128, 0, stream>>>(x, WallT, bfv, bgv, bhv, fg, hT);
    attn_kernel<<<512, 256, 0, stream>>>(fg, hT, x, scale, out);
}